// Round 4
// baseline (1960.845 us; speedup 1.0000x reference)
//
#include <hip/hip_runtime.h>
#include <math.h>

typedef short bf16x8 __attribute__((ext_vector_type(8)));
typedef float f32x4  __attribute__((ext_vector_type(4)));
typedef unsigned short u16;

// Problem constants (B=4096, T=100, F=13, H=100)
#define B_  4096
#define T_  100
#define F_  13
#define NB  256    // blocks
#define MR  16     // rows per block
#define S0  136    // A0 row stride (u16): [0..100)=h0, [100..113)=x, rest 0
#define S1  232    // A1 row stride (u16): [0..100)=h0n, [100..200)=h1, rest 0
#define A0SZ (MR * S0)   // 2176 u16 per buffer
#define A1SZ (MR * S1)   // 3712 u16 per buffer

// ws layout (bytes), total 651,264 (proven available in round 3)
#define O_HIST   0u
#define O_ROWMAP 512u
#define O_BIAS0  16896u
#define O_BIAS1  18688u
#define O_B0     20480u    // 7ct*16384 u16 = 229376 B
#define O_B1     249856u   // 7ct*28672 u16 = 401408 B -> 651264

// B-fragment layout (u16 index), per-wave-contiguous slices:
//   B0: ct*16384 + ((kt*4+g)*2+pass)*512 + lane*8 + j     (kt<4)
//   B1: ct*28672 + ((kt*4+g)*2+pass)*512 + lane*8 + j     (kt<7)
// lane's element j holds W_pass[k = kt*32 + (lane>>4)*8 + j][col = g*100... ]
// cols gate-major: row = g*100 + (ct*16 + (lane&15))), zero-padded.

__device__ __forceinline__ float sigmoid_f(float v) {
    return 1.0f / (1.0f + __expf(-v));
}
__device__ __forceinline__ float tanh_f(float v) {
    float e = __expf(2.0f * v);
    return 1.0f - 2.0f / (e + 1.0f);
}
__device__ __forceinline__ void split_bf16(float v, u16& hi, u16& lo) {
    unsigned u = __float_as_uint(v);
    hi = (u16)(u >> 16);
    float rem = v - __uint_as_float(u & 0xFFFF0000u);
    unsigned r = __float_as_uint(rem);
    unsigned rnd = r + 0x7FFFu + ((r >> 16) & 1u);
    lo = (u16)(rnd >> 16);
}
__device__ __forceinline__ float bf16_to_f(u16 b) {
    return __uint_as_float(((unsigned)b) << 16);
}

// Cross-wave data flows ONLY through LDS in the main loop -> lgkmcnt-only
// barrier: lets prefetched global B-frag loads stay in flight across it.
__device__ __forceinline__ void block_sync() {
    asm volatile("s_waitcnt lgkmcnt(0)\n\ts_barrier" ::: "memory");
}

// ---------------- prep: counting sort of rows by length ----------------
__global__ void k_hist(const int* __restrict__ len, int* __restrict__ hist) {
    int b = blockIdx.x * blockDim.x + threadIdx.x;
    if (b < B_) atomicAdd(&hist[len[b]], 1);
}
__global__ void k_scan(int* __restrict__ hist) {
    if (threadIdx.x == 0 && blockIdx.x == 0) {
        int acc = 0;
        for (int l = 0; l <= 100; ++l) { int c = hist[l]; hist[l] = acc; acc += c; }
    }
}
__global__ void k_scatter(const int* __restrict__ len, int* __restrict__ hist,
                          int* __restrict__ rowmap) {
    int b = blockIdx.x * blockDim.x + threadIdx.x;
    if (b < B_) {
        int pos = atomicAdd(&hist[len[b]], 1);
        rowmap[pos] = b;
    }
}

// ---------------- prep: biases (gate-major, padded to 112) ----------------
__global__ void k_prep_bias(const float* __restrict__ bih0, const float* __restrict__ bhh0,
                            const float* __restrict__ bih1, const float* __restrict__ bhh1,
                            float* __restrict__ bias0, float* __restrict__ bias1) {
    int idx = blockIdx.x * blockDim.x + threadIdx.x;
    if (idx < 448) {
        int g = idx / 112, cell = idx % 112;
        float v0 = 0.f, v1 = 0.f;
        if (cell < 100) {
            int row = g * 100 + cell;
            v0 = bih0[row] + bhh0[row];
            v1 = bih1[row] + bhh1[row];
        }
        bias0[idx] = v0; bias1[idx] = v1;
    }
}

// ---------------- prep: weights -> per-wave-contiguous B-frag order --------
__global__ void k_prep_b(const float* __restrict__ Wih0, const float* __restrict__ Whh0,
                         const float* __restrict__ Wih1, const float* __restrict__ Whh1,
                         u16* __restrict__ B0, u16* __restrict__ B1) {
    int idx = blockIdx.x * blockDim.x + threadIdx.x;
    if (idx < 7 * 28672) {   // B1
        int ct = idx / 28672, r = idx % 28672;
        int chunk = r >> 9, e = r & 511;
        int kt = chunk >> 3, g = (chunk >> 1) & 3, pass = chunk & 1;
        int lane = e >> 3, j = e & 7;
        int k = kt * 32 + (lane >> 4) * 8 + j;
        int cell = ct * 16 + (lane & 15);
        float w = 0.f;
        if (cell < 100) {
            int row = g * 100 + cell;
            if (k < 100)      w = Wih1[row * 100 + k];
            else if (k < 200) w = Whh1[row * 100 + (k - 100)];
        }
        u16 hi, lo; split_bf16(w, hi, lo);
        B1[idx] = pass ? lo : hi;
    }
    if (idx < 7 * 16384) {   // B0
        int ct = idx / 16384, r = idx % 16384;
        int chunk = r >> 9, e = r & 511;
        int kt = chunk >> 3, g = (chunk >> 1) & 3, pass = chunk & 1;
        int lane = e >> 3, j = e & 7;
        int k = kt * 32 + (lane >> 4) * 8 + j;
        int cell = ct * 16 + (lane & 15);
        float w = 0.f;
        if (cell < 100) {
            int row = g * 100 + cell;
            if (k < 100)      w = Whh0[row * 100 + k];      // h0 part
            else if (k < 113) w = Wih0[row * 13 + (k - 100)]; // x part
        }
        u16 hi, lo; split_bf16(w, hi, lo);
        B0[idx] = pass ? lo : hi;
    }
}

// ---------------- helpers ----------------
__device__ __forceinline__ void loadBK(const u16* __restrict__ bp, int chunkBase,
                                       bf16x8 h[4], bf16x8 l[4]) {
#pragma unroll
    for (int g = 0; g < 4; ++g) {
        h[g] = *(const bf16x8*)(bp + (size_t)(chunkBase + g * 2 + 0) * 512);
        l[g] = *(const bf16x8*)(bp + (size_t)(chunkBase + g * 2 + 1) * 512);
    }
}
__device__ __forceinline__ void mfma3(const bf16x8 ah, const bf16x8 al,
                                      const bf16x8 bh[4], const bf16x8 bl[4],
                                      f32x4 P[4], f32x4 Q[4]) {
#pragma unroll
    for (int g = 0; g < 4; ++g) {
        P[g] = __builtin_amdgcn_mfma_f32_16x16x32_bf16(ah, bh[g], P[g], 0, 0, 0);
        Q[g] = __builtin_amdgcn_mfma_f32_16x16x32_bf16(al, bh[g], Q[g], 0, 0, 0);
        Q[g] = __builtin_amdgcn_mfma_f32_16x16x32_bf16(ah, bl[g], Q[g], 0, 0, 0);
    }
}

// ---------------- main persistent MFMA LSTM ----------------
// 256 blocks x 16 rows, 8 waves: waves 0..6 = cell-tiles (16 cols each, all 4
// gates), wave 7 = x prefetcher. h-state double-buffered in LDS (2 barriers /
// step); B-frags streamed from L2 with one-chunk-ahead register prefetch that
// crosses barriers (lgkm-only barrier keeps vmcnt in flight).
__global__ __launch_bounds__(512) void k_lstm(
    const float* __restrict__ x, const int* __restrict__ lengths,
    const int* __restrict__ rowmap,
    const u16* __restrict__ B0, const u16* __restrict__ B1,
    const float* __restrict__ bias0, const float* __restrict__ bias1,
    const float* __restrict__ Wfc, const float* __restrict__ bfc,
    float* __restrict__ out)
{
    __shared__ __align__(16) u16 Ah0[2 * A0SZ];
    __shared__ __align__(16) u16 Al0[2 * A0SZ];
    __shared__ __align__(16) u16 Ah1[2 * A1SZ];
    __shared__ __align__(16) u16 Al1[2 * A1SZ];
    __shared__ int sRow[MR], sLen[MR], sTmax;

    const int tid = threadIdx.x;
    const int wv = tid >> 6, lane = tid & 63;

    if (tid < MR) {
        int r = rowmap[blockIdx.x * MR + tid];
        sRow[tid] = r; sLen[tid] = lengths[r];
    }
    if (tid == 0) {  // wave 0 just wrote sLen; same-wave LDS dep is tracked
        int m = 0;
        for (int i = 0; i < MR; ++i) m = max(m, sLen[i]);
        sTmax = m;
    }
    {   // zero both buffers of all 4 arrays
        unsigned* p0 = (unsigned*)Ah0; unsigned* p1 = (unsigned*)Al0;
        unsigned* p2 = (unsigned*)Ah1; unsigned* p3 = (unsigned*)Al1;
        for (int i = tid; i < A0SZ; i += 512) { p0[i] = 0; p1[i] = 0; }
        for (int i = tid; i < A1SZ; i += 512) { p2[i] = 0; p3[i] = 0; }
    }
    __syncthreads();
    const int Tmax = sTmax;

    const int n = lane & 15, q = lane >> 4;
    const int ct = wv;              // for wv<7
    const int cell = ct * 16 + n;
    const bool cw = (wv < 7) && (cell < 100);

    // per-wave state
    float b0v[4], b1v[4], c0[4], c1[4];
    int   lenR[4];
    int   offA0 = 0, offA1 = 0;
    const u16* b0p = B0; const u16* b1p = B1;
    bf16x8 pfh[4], pfl[4];          // prefetched chunk-0 of next GEMM

    // x-wave state
    float xv[4]; int xok[4]; size_t xg[4]; int xoff[4];

    if (wv < 7) {
#pragma unroll
        for (int g = 0; g < 4; ++g) {
            b0v[g] = bias0[g * 112 + cell];
            b1v[g] = bias1[g * 112 + cell];
        }
#pragma unroll
        for (int r = 0; r < 4; ++r) {
            lenR[r] = sLen[q * 4 + r];
            c0[r] = 0.f; c1[r] = 0.f;
        }
        offA0 = n * S0 + q * 8;
        offA1 = n * S1 + q * 8;
        b0p = B0 + (size_t)ct * 16384 + lane * 8;
        b1p = B1 + (size_t)ct * 28672 + lane * 8;
        loadBK(b0p, 0, pfh, pfl);   // L0 chunk0 for t=0
    } else {
#pragma unroll
        for (int i = 0; i < 4; ++i) {
            int e = i * 64 + lane;
            xok[i] = (e < MR * F_);
            int r = xok[i] ? (e / F_) : 0;
            int f = xok[i] ? (e - F_ * r) : 0;
            xg[i]   = (size_t)sRow[r] * (T_ * F_) + f;
            xoff[i] = r * S0 + 100 + f;
            if (xok[i]) {           // x(0) -> buffer 0
                u16 hi, lo; split_bf16(x[xg[i]], hi, lo);
                Ah0[xoff[i]] = hi; Al0[xoff[i]] = lo;
            }
        }
    }

    for (int t = 0; t < Tmax; ++t) {
        const int rd = t & 1, wr = rd ^ 1;
        block_sync();   // x(t)/h0(t-1) in Ah0[rd]; h1(t-1) settled

        if (wv < 7) {
            // ---------- Phase A: layer-0 GEMM ----------
            f32x4 P[4], Q[4];
#pragma unroll
            for (int g = 0; g < 4; ++g) {
                P[g] = (f32x4){b0v[g], b0v[g], b0v[g], b0v[g]};
                Q[g] = (f32x4){0.f, 0.f, 0.f, 0.f};
            }
            bf16x8 ch[2][4], cl[2][4];
#pragma unroll
            for (int g = 0; g < 4; ++g) { ch[0][g] = pfh[g]; cl[0][g] = pfl[g]; }
            const u16* a0 = &Ah0[rd * A0SZ + offA0];
            const u16* a0l = &Al0[rd * A0SZ + offA0];
#pragma unroll
            for (int kt = 0; kt < 4; ++kt) {
                if (kt < 3) loadBK(b0p, (kt + 1) * 8, ch[(kt + 1) & 1], cl[(kt + 1) & 1]);
                else        loadBK(b1p, 0, pfh, pfl);     // L1 chunk0 (crosses barrier)
                bf16x8 ah = *(const bf16x8*)(a0 + kt * 32);
                bf16x8 al = *(const bf16x8*)(a0l + kt * 32);
                mfma3(ah, al, ch[kt & 1], cl[kt & 1], P, Q);
            }
            // pointwise layer 0 + state writes (into wr buffers)
            u16* wAh0 = &Ah0[wr * A0SZ]; u16* wAl0 = &Al0[wr * A0SZ];
            u16* wAh1 = &Ah1[wr * A1SZ]; u16* wAl1 = &Al1[wr * A1SZ];
#pragma unroll
            for (int r = 0; r < 4; ++r) {
                float zi = P[0][r] + Q[0][r], zf = P[1][r] + Q[1][r];
                float zg = P[2][r] + Q[2][r], zo = P[3][r] + Q[3][r];
                float cn = sigmoid_f(zf) * c0[r] + sigmoid_f(zi) * tanh_f(zg);
                float hn = sigmoid_f(zo) * tanh_f(cn);
                if (t < lenR[r]) {
                    c0[r] = cn;
                    if (cw) {
                        int row = q * 4 + r;
                        u16 hi, lo; split_bf16(hn, hi, lo);
                        wAh0[row * S0 + cell] = hi; wAl0[row * S0 + cell] = lo;
                        wAh1[row * S1 + cell] = hi; wAl1[row * S1 + cell] = lo;
                    }
                }
            }
        } else {
            if (t + 1 < Tmax) {
#pragma unroll
                for (int i = 0; i < 4; ++i)
                    if (xok[i]) xv[i] = x[xg[i] + (size_t)(t + 1) * F_];
            }
        }

        block_sync();   // h0n(t) in Ah1[wr]

        if (wv < 7) {
            // ---------- Phase B: layer-1 GEMM ----------
            f32x4 P[4], Q[4];
#pragma unroll
            for (int g = 0; g < 4; ++g) {
                P[g] = (f32x4){b1v[g], b1v[g], b1v[g], b1v[g]};
                Q[g] = (f32x4){0.f, 0.f, 0.f, 0.f};
            }
            bf16x8 ch[2][4], cl[2][4];
#pragma unroll
            for (int g = 0; g < 4; ++g) { ch[0][g] = pfh[g]; cl[0][g] = pfl[g]; }
            const u16* a1 = &Ah1[wr * A1SZ + offA1];
            const u16* a1l = &Al1[wr * A1SZ + offA1];
#pragma unroll
            for (int kt = 0; kt < 7; ++kt) {
                if (kt < 6) loadBK(b1p, (kt + 1) * 8, ch[(kt + 1) & 1], cl[(kt + 1) & 1]);
                else        loadBK(b0p, 0, pfh, pfl);     // next step's L0 chunk0
                bf16x8 ah = *(const bf16x8*)(a1 + kt * 32);
                bf16x8 al = *(const bf16x8*)(a1l + kt * 32);
                mfma3(ah, al, ch[kt & 1], cl[kt & 1], P, Q);
            }
            // pointwise layer 1; h1(t) -> rd buffer (read again at t+1 from its wr)
            u16* wAh1r = &Ah1[rd * A1SZ]; u16* wAl1r = &Al1[rd * A1SZ];
#pragma unroll
            for (int r = 0; r < 4; ++r) {
                float zi = P[0][r] + Q[0][r], zf = P[1][r] + Q[1][r];
                float zg = P[2][r] + Q[2][r], zo = P[3][r] + Q[3][r];
                float cn = sigmoid_f(zf) * c1[r] + sigmoid_f(zi) * tanh_f(zg);
                float hn = sigmoid_f(zo) * tanh_f(cn);
                if (t < lenR[r]) {
                    c1[r] = cn;
                    if (cw) {
                        int row = q * 4 + r;
                        u16 hi, lo; split_bf16(hn, hi, lo);
                        wAh1r[row * S1 + 100 + cell] = hi;
                        wAl1r[row * S1 + 100 + cell] = lo;
                    }
                }
            }
        } else {
            if (t + 1 < Tmax) {
                u16* wAh0 = &Ah0[wr * A0SZ]; u16* wAl0 = &Al0[wr * A0SZ];
#pragma unroll
                for (int i = 0; i < 4; ++i) if (xok[i]) {
                    u16 hi, lo; split_bf16(xv[i], hi, lo);
                    wAh0[xoff[i]] = hi; wAl0[xoff[i]] = lo;
                }
            }
        }
    }
    __syncthreads();

    // out[b] = W_fc . h1(len-1) + b_fc ; h1(len-1) lives in buffer (len-1)&1
    if (tid < MR) {
        int p = (sLen[tid] - 1) & 1;
        const u16* hh = &Ah1[p * A1SZ + tid * S1 + 100];
        const u16* hl = &Al1[p * A1SZ + tid * S1 + 100];
        float s = bfc[0];
        for (int j = 0; j < 100; ++j)
            s = fmaf(Wfc[j], bf16_to_f(hh[j]) + bf16_to_f(hl[j]), s);
        out[sRow[tid]] = s;
    }
}

// ---------------- launch ----------------
extern "C" void kernel_launch(void* const* d_in, const int* in_sizes, int n_in,
                              void* d_out, int out_size, void* d_ws, size_t ws_size,
                              hipStream_t stream) {
    const float* x    = (const float*)d_in[0];
    const int*   len  = (const int*)d_in[1];
    const float* Wih0 = (const float*)d_in[2];
    const float* Whh0 = (const float*)d_in[3];
    const float* bih0 = (const float*)d_in[4];
    const float* bhh0 = (const float*)d_in[5];
    const float* Wih1 = (const float*)d_in[6];
    const float* Whh1 = (const float*)d_in[7];
    const float* bih1 = (const float*)d_in[8];
    const float* bhh1 = (const float*)d_in[9];
    const float* Wfc  = (const float*)d_in[10];
    const float* bfc  = (const float*)d_in[11];
    float* out = (float*)d_out;

    char* ws = (char*)d_ws;   // uses 651,264 bytes
    int*   hist   = (int*)(ws + O_HIST);
    int*   rowmap = (int*)(ws + O_ROWMAP);
    float* bias0  = (float*)(ws + O_BIAS0);
    float* bias1  = (float*)(ws + O_BIAS1);
    u16*   B0     = (u16*)(ws + O_B0);
    u16*   B1     = (u16*)(ws + O_B1);

    hipMemsetAsync(hist, 0, 512, stream);
    k_hist<<<16, 256, 0, stream>>>(len, hist);
    k_scan<<<1, 64, 0, stream>>>(hist);
    k_scatter<<<16, 256, 0, stream>>>(len, hist, rowmap);
    k_prep_bias<<<2, 256, 0, stream>>>(bih0, bhh0, bih1, bhh1, bias0, bias1);
    k_prep_b<<<(7 * 28672 + 255) / 256, 256, 0, stream>>>(Wih0, Whh0, Wih1, Whh1, B0, B1);
    k_lstm<<<NB, 512, 0, stream>>>(x, len, rowmap, B0, B1, bias0, bias1, Wfc, bfc, out);
}